// Round 14
// baseline (100.204 us; speedup 1.0000x reference)
//
#include <hip/hip_runtime.h>

#define BB 2
#define CC 64
#define HH 128
#define WW 128
#define NN (HH*WW)          // 16384 queries per batch
#define MM ((HH/2)*(WW/2))  // 4096 keys per batch
#define CV 32
#define LOG2E 1.44269504088896f

typedef __attribute__((ext_vector_type(8))) short bf16x8;
typedef __attribute__((ext_vector_type(4))) float f32x4;
typedef unsigned int uint32;

union U8 { bf16x8 v; uint32 u[4]; };

__device__ __forceinline__ short f2bf(float f) {
    union { float f; unsigned u; } v; v.f = f;
    unsigned u = v.u + 0x7fffu + ((v.u >> 16) & 1u);   // RNE
    return (short)(u >> 16);
}
__device__ __forceinline__ uint32 pack2bf(float lo, float hi) {
    return (uint32)(unsigned short)f2bf(lo) | ((uint32)(unsigned short)f2bf(hi) << 16);
}
// 1-instr truncation pack via v_perm_b32; downward bias cancels in P/l ratio
__device__ __forceinline__ uint32 packperm(float lo, float hi) {
    union { float f; uint32 u; } a, b; a.f = lo; b.f = hi;
    return __builtin_amdgcn_perm(b.u, a.u, 0x07060302u);
}
// async global->LDS DMA, 16B/lane; LDS dst = wave-uniform base + lane*16
__device__ __forceinline__ void gl_lds16(const short* g, short* l) {
    __builtin_amdgcn_global_load_lds(
        (const __attribute__((address_space(1))) void*)g,
        (__attribute__((address_space(3))) void*)l, 16, 0, 0);
}
// R14: AITER-style partial-drain barrier. __syncthreads() emits
// "s_waitcnt vmcnt(0); s_barrier" — drains the just-issued prefetch DMAs
// every stage (the measured ~1200+cyc/stage stall). Here each wave waits
// only for DMAs OLDER than the N it just issued (its own prefetch stays in
// flight across the barrier), then barriers. vmcnt is per-wave, so each
// wave certifies its own stage-sc writes before entering; after the
// barrier all stage-sc LDS data is visible to all waves.
#define WAITB3() asm volatile("s_waitcnt vmcnt(3)\ns_barrier" ::: "memory")
#define WAITB2() asm volatile("s_waitcnt vmcnt(2)\ns_barrier" ::: "memory")

// ---------------------------------------------------------------------------
// Kernel 1 = R13's proj, byte-identical (P3 z-split + readfirstlane; ~14-16us).
// ---------------------------------------------------------------------------
__global__ __launch_bounds__(256, 4) void proj_kernel(
    const float* __restrict__ x, const float* __restrict__ wt,
    const float* __restrict__ wp, const float* __restrict__ wg,
    short* __restrict__ Qb, short* __restrict__ Kb, short* __restrict__ Vt)
{
    __shared__ float plds[8192];
    __shared__ float phi_lds[512];
    int tid = threadIdx.x;
    int px = tid & 63, part = tid >> 6;
    int sb = blockIdx.x >> 2, cq = blockIdx.x & 3;
    int b = blockIdx.y, z = blockIdx.z;
    int row = px >> 5, col = cq*32 + (px & 31);
    int n = (2*sb + row)*WW + col;
    int wbase = __builtin_amdgcn_readfirstlane(part*16);

    float xv[16];
    #pragma unroll
    for (int i = 0; i < 16; ++i)
        xv[i] = x[((b*CC + part*16 + i) << 14) + n];

    if (z == 0) {
        float po[16];
        #pragma unroll
        for (int o = 0; o < 8; ++o) {
            float a = 0.f;
            #pragma unroll
            for (int i = 0; i < 16; ++i) a += wt[o*64 + wbase + i]*xv[i];
            po[o] = a;
        }
        #pragma unroll
        for (int o = 0; o < 8; ++o) {
            float a = 0.f;
            #pragma unroll
            for (int i = 0; i < 16; ++i) a += wp[o*64 + wbase + i]*xv[i];
            po[8+o] = a;
        }
        #pragma unroll
        for (int o = 0; o < 16; ++o) plds[(o*4 + part)*64 + px] = po[o];
        __syncthreads();
        int og = tid >> 6;
        float sm[4];
        #pragma unroll
        for (int j = 0; j < 4; ++j) {
            int o = og*4 + j;
            sm[j] = (plds[(o*4+0)*64+px] + plds[(o*4+1)*64+px])
                  + (plds[(o*4+2)*64+px] + plds[(o*4+3)*64+px]);
        }
        if (og < 2) {
            uint2 val;
            val.x = pack2bf(sm[0]*LOG2E, sm[1]*LOG2E);
            val.y = pack2bf(sm[2]*LOG2E, sm[3]*LOG2E);
            ((uint2*)Qb)[(b*NN + n)*2 + og] = val;
        } else {
            #pragma unroll
            for (int j = 0; j < 4; ++j)
                phi_lds[((og-2)*4 + j)*64 + px] = sm[j];
        }
        __syncthreads();
        if (tid < 128) {
            int mm = tid & 15, ch = tid >> 4;
            int p00 = 2*mm, p01 = p00+1, p10 = 32+2*mm, p11 = p10+1;
            float mx = fmaxf(fmaxf(phi_lds[ch*64+p00], phi_lds[ch*64+p01]),
                             fmaxf(phi_lds[ch*64+p10], phi_lds[ch*64+p11]));
            int m = sb*64 + cq*16 + mm;
            Kb[(b*MM + m)*8 + ch] = f2bf(mx);
        }
    } else {
        float po[32];
        #pragma unroll
        for (int o = 0; o < 32; ++o) {
            float a = 0.f;
            #pragma unroll
            for (int i = 0; i < 16; ++i) a += wg[o*64 + wbase + i]*xv[i];
            po[o] = a;
        }
        #pragma unroll
        for (int o = 0; o < 32; ++o) plds[(o*4 + part)*64 + px] = po[o];
        __syncthreads();
        int og = tid >> 6;
        float sm[8];
        #pragma unroll
        for (int j = 0; j < 8; ++j) {
            int o = og*8 + j;
            sm[j] = (plds[(o*4+0)*64+px] + plds[(o*4+1)*64+px])
                  + (plds[(o*4+2)*64+px] + plds[(o*4+3)*64+px]);
        }
        __syncthreads();
        #pragma unroll
        for (int j = 0; j < 8; ++j)
            plds[(og*8 + j)*64 + px] = sm[j];
        __syncthreads();
        int mm = tid & 15, chb = tid >> 4;
        int p00 = 2*mm, p01 = p00+1, p10 = 32+2*mm, p11 = p10+1;
        int w64 = cq*16 + mm;
        int hh = w64 >> 5, w = w64 & 31;
        int slot = ((w >> 2) & 3)*8 + (w & 3) + ((w >> 4) << 2);
        int pos64 = hh*32 + slot;
        #pragma unroll
        for (int j = 0; j < 2; ++j) {
            int ch = chb*2 + j;
            float mx = fmaxf(fmaxf(plds[ch*64+p00], plds[ch*64+p01]),
                             fmaxf(plds[ch*64+p10], plds[ch*64+p11]));
            int colv = (pos64 >> 3) ^ (ch & 7);
            Vt[(b*CV + ch)*MM + sb*64 + colv*8 + (pos64 & 7)] = f2bf(mx);
        }
    }
}

// ---------------------------------------------------------------------------
// Kernel 2 = R13's attn (R9 v5) with ONE change: the per-stage
// __syncthreads() replaced by s_waitcnt vmcnt(3|2) + raw s_barrier, so the
// stage's prefetch DMAs stay in flight across the barrier (AITER pattern).
// ---------------------------------------------------------------------------
__global__ __launch_bounds__(512, 4) void attn_kernel(
    const short* __restrict__ Qb, const short* __restrict__ Kb,
    const short* __restrict__ Vt, const float* __restrict__ x,
    const float* __restrict__ wo, const float* __restrict__ gamma,
    float* __restrict__ out)
{
    __shared__ short ldsK[2][4][512];    // [buf][qtr][64key x 8ch]
    __shared__ short ldsV[2][4][2048];   // [buf][qtr][32ch x 64key swizzled]
    __shared__ float comb[2][2][576];    // [qpair][tile][lane*9]
    int tid = threadIdx.x;
    int wave = tid >> 6, lane = tid & 63;
    int quad = lane >> 4, c15 = lane & 15, sw = c15 & 7;
    int qtr = wave >> 1, qpair = wave & 1;
    int blk = blockIdx.x;
    int b = blk >> 8;
    int qblk = (blk & 255)*64;
    int q0 = qblk + qpair*32;            // tiles q0, q0+16

    const f32x4 zero4 = {0.f, 0.f, 0.f, 0.f};
    bf16x8 zero8 = (bf16x8)0;
    U8 ones; ones.u[0] = ones.u[1] = ones.u[2] = ones.u[3] = 0x3F803F80u;

    bf16x8 bq0 = (quad == 0) ? ((const bf16x8*)Qb)[b*NN + q0 + c15]      : zero8;
    bf16x8 bq1 = (quad == 0) ? ((const bf16x8*)Qb)[b*NN + q0 + 16 + c15] : zero8;

    // DMA source/dest: wave (qtr,qpair) stages its quarter's V channel-half;
    // qpair==0 waves also stage the quarter's K (3 DMAs/stage vs 2).
    const short* vsrcA = Vt + ((size_t)(b*CV + 16*qpair + (lane >> 3)))*MM
                       + qtr*1024 + (lane & 7)*8;
    const short* vsrcB = vsrcA + 8*MM;                  // channels +8
    const short* ksrc  = Kb + (size_t)b*MM*8 + (qtr*1024 + lane)*8;
    short* vdstA[2] = { &ldsV[0][qtr][qpair*1024 + lane*8],
                        &ldsV[1][qtr][qpair*1024 + lane*8] };
    short* vdstB[2] = { vdstA[0] + 512, vdstA[1] + 512 };
    short* kdst[2]  = { &ldsK[0][qtr][lane*8], &ldsK[1][qtr][lane*8] };

    {   // stage 0 DMA
        gl_lds16(vsrcA, vdstA[0]);
        gl_lds16(vsrcB, vdstB[0]);
        if (qpair == 0) gl_lds16(ksrc, kdst[0]);
    }
    // Only Q loads + stage-0 DMAs outstanding; partial-drain barrier works
    // for the prologue too (prefetch for stage 1 not yet issued, so wait
    // covers stage 0 exactly once inside the loop).

    f32x4 D0A = zero4, D1A = zero4, DlA = zero4;
    f32x4 D0B = zero4, D1B = zero4, DlB = zero4;

    for (int sc = 0; sc < 16; ++sc) {
        int scn = (sc + 1 > 15) ? 15 : sc + 1;
        int nb = (sc + 1) & 1;
        // prefetch next stage straight into the other LDS buffer
        gl_lds16(vsrcA + scn*64, vdstA[nb]);
        gl_lds16(vsrcB + scn*64, vdstB[nb]);
        if (qpair == 0) gl_lds16(ksrc + scn*512, kdst[nb]);

        // partial drain: everything OLDER than this stage's prefetch has
        // landed (incl. previous stage's staging); prefetch stays in flight.
        if (qpair == 0) WAITB3(); else WAITB2();

        const short* bk = ldsK[sc & 1][qtr];
        const short* bv = ldsV[sc & 1][qtr];
        #pragma unroll
        for (int h = 0; h < 2; ++h) {
            bf16x8 kf0 = *(const bf16x8*)(bk + (h*32 + c15)*8);
            bf16x8 kf1 = *(const bf16x8*)(bk + (h*32 + 16 + c15)*8);
            int col8 = ((h*4 + quad) ^ sw)*8;
            bf16x8 a0 = *(const bf16x8*)(bv + c15*64 + col8);
            bf16x8 a1 = *(const bf16x8*)(bv + (16 + c15)*64 + col8);
            f32x4 s0A = __builtin_amdgcn_mfma_f32_16x16x32_bf16(kf0, bq0, zero4, 0, 0, 0);
            f32x4 s1A = __builtin_amdgcn_mfma_f32_16x16x32_bf16(kf1, bq0, zero4, 0, 0, 0);
            f32x4 s0B = __builtin_amdgcn_mfma_f32_16x16x32_bf16(kf0, bq1, zero4, 0, 0, 0);
            f32x4 s1B = __builtin_amdgcn_mfma_f32_16x16x32_bf16(kf1, bq1, zero4, 0, 0, 0);
            U8 bpA, bpB;
            bpA.u[0] = packperm(__builtin_amdgcn_exp2f(s0A[0]), __builtin_amdgcn_exp2f(s0A[1]));
            bpA.u[1] = packperm(__builtin_amdgcn_exp2f(s0A[2]), __builtin_amdgcn_exp2f(s0A[3]));
            bpA.u[2] = packperm(__builtin_amdgcn_exp2f(s1A[0]), __builtin_amdgcn_exp2f(s1A[1]));
            bpA.u[3] = packperm(__builtin_amdgcn_exp2f(s1A[2]), __builtin_amdgcn_exp2f(s1A[3]));
            bpB.u[0] = packperm(__builtin_amdgcn_exp2f(s0B[0]), __builtin_amdgcn_exp2f(s0B[1]));
            bpB.u[1] = packperm(__builtin_amdgcn_exp2f(s0B[2]), __builtin_amdgcn_exp2f(s0B[3]));
            bpB.u[2] = packperm(__builtin_amdgcn_exp2f(s1B[0]), __builtin_amdgcn_exp2f(s1B[1]));
            bpB.u[3] = packperm(__builtin_amdgcn_exp2f(s1B[2]), __builtin_amdgcn_exp2f(s1B[3]));
            D0A = __builtin_amdgcn_mfma_f32_16x16x32_bf16(a0, bpA.v, D0A, 0, 0, 0);
            D1A = __builtin_amdgcn_mfma_f32_16x16x32_bf16(a1, bpA.v, D1A, 0, 0, 0);
            DlA = __builtin_amdgcn_mfma_f32_16x16x32_bf16(ones.v, bpA.v, DlA, 0, 0, 0);
            D0B = __builtin_amdgcn_mfma_f32_16x16x32_bf16(a0, bpB.v, D0B, 0, 0, 0);
            D1B = __builtin_amdgcn_mfma_f32_16x16x32_bf16(a1, bpB.v, D1B, 0, 0, 0);
            DlB = __builtin_amdgcn_mfma_f32_16x16x32_bf16(ones.v, bpB.v, DlB, 0, 0, 0);
        }
    }
    __syncthreads();    // full drain (incl. final redundant prefetch) before combine

    // combine 4 quarter partials (stride-9: conflict-free)
    #pragma unroll
    for (int r = 1; r < 4; ++r) {
        if (qtr == r) {
            float* cA = &comb[qpair][0][lane*9];
            cA[0]=D0A[0]; cA[1]=D0A[1]; cA[2]=D0A[2]; cA[3]=D0A[3];
            cA[4]=D1A[0]; cA[5]=D1A[1]; cA[6]=D1A[2]; cA[7]=D1A[3];
            cA[8]=DlA[0];
            float* cB = &comb[qpair][1][lane*9];
            cB[0]=D0B[0]; cB[1]=D0B[1]; cB[2]=D0B[2]; cB[3]=D0B[3];
            cB[4]=D1B[0]; cB[5]=D1B[1]; cB[6]=D1B[2]; cB[7]=D1B[3];
            cB[8]=DlB[0];
        }
        __syncthreads();
        if (qtr == 0) {
            const float* cA = &comb[qpair][0][lane*9];
            D0A[0]+=cA[0]; D0A[1]+=cA[1]; D0A[2]+=cA[2]; D0A[3]+=cA[3];
            D1A[0]+=cA[4]; D1A[1]+=cA[5]; D1A[2]+=cA[6]; D1A[3]+=cA[7];
            DlA[0]+=cA[8];
            const float* cB = &comb[qpair][1][lane*9];
            D0B[0]+=cB[0]; D0B[1]+=cB[1]; D0B[2]+=cB[2]; D0B[3]+=cB[3];
            D1B[0]+=cB[4]; D1B[1]+=cB[5]; D1B[2]+=cB[6]; D1B[3]+=cB[7];
            DlB[0]+=cB[8];
        }
        __syncthreads();
    }
    if (qtr != 0) return;       // no barriers past this point

    float rlA = 1.0f / DlA[0];
    float rlB = 1.0f / DlB[0];
    U8 ByA, ByB;
    ByA.u[0] = pack2bf(D0A[0]*rlA, D0A[1]*rlA); ByA.u[1] = pack2bf(D0A[2]*rlA, D0A[3]*rlA);
    ByA.u[2] = pack2bf(D1A[0]*rlA, D1A[1]*rlA); ByA.u[3] = pack2bf(D1A[2]*rlA, D1A[3]*rlA);
    ByB.u[0] = pack2bf(D0B[0]*rlB, D0B[1]*rlB); ByB.u[1] = pack2bf(D0B[2]*rlB, D0B[3]*rlB);
    ByB.u[2] = pack2bf(D1B[0]*rlB, D1B[1]*rlB); ByB.u[3] = pack2bf(D1B[2]*rlB, D1B[3]*rlB);

    float gam = gamma[0];
    #pragma unroll
    for (int t = 0; t < 4; ++t) {
        int co = t*16 + c15;
        float4 wlo = *(const float4*)(wo + co*32 + quad*4);
        float4 whi = *(const float4*)(wo + co*32 + 16 + quad*4);
        U8 aw;
        aw.u[0] = pack2bf(wlo.x, wlo.y); aw.u[1] = pack2bf(wlo.z, wlo.w);
        aw.u[2] = pack2bf(whi.x, whi.y); aw.u[3] = pack2bf(whi.z, whi.w);
        f32x4 oA = __builtin_amdgcn_mfma_f32_16x16x32_bf16(aw.v, ByA.v, zero4, 0, 0, 0);
        f32x4 oB = __builtin_amdgcn_mfma_f32_16x16x32_bf16(aw.v, ByB.v, zero4, 0, 0, 0);
        #pragma unroll
        for (int r2 = 0; r2 < 4; ++r2) {
            int co_r = t*16 + quad*4 + r2;
            int base = ((b*CC + co_r) << 14) + q0 + c15;
            out[base]      = x[base]      + gam*oA[r2];
            out[base + 16] = x[base + 16] + gam*oB[r2];
        }
    }
}

// ---------------------------------------------------------------------------
// Workspace: Qb 512K @ 0, Kb 128K @ 524288, Vt 512K @ 655360.
// ---------------------------------------------------------------------------
extern "C" void kernel_launch(void* const* d_in, const int* in_sizes, int n_in,
                              void* d_out, int out_size, void* d_ws, size_t ws_size,
                              hipStream_t stream) {
    const float* x     = (const float*)d_in[0];
    const float* wt    = (const float*)d_in[1];
    const float* wp    = (const float*)d_in[2];
    const float* wg    = (const float*)d_in[3];
    const float* wo    = (const float*)d_in[4];
    const float* gamma = (const float*)d_in[5];
    float* out = (float*)d_out;

    char* ws = (char*)d_ws;
    short* Qb = (short*)(ws);
    short* Kb = (short*)(ws + 524288);
    short* Vt = (short*)(ws + 655360);

    dim3 g1(256, BB, 2);
    proj_kernel<<<g1, 256, 0, stream>>>(x, wt, wp, wg, Qb, Kb, Vt);
    attn_kernel<<<BB*NN/64, 512, 0, stream>>>(Qb, Kb, Vt, x, wo, gamma, out);
}